// Round 11
// baseline (316.789 us; speedup 1.0000x reference)
//
#include <hip/hip_runtime.h>
#include <hip/hip_fp16.h>

#define NNODES 100000
#define NEDGES 800000
#define NGRAPHS 5000
#define FN 11
#define FE 4
#define H1C 32
#define H2C 16

typedef _Float16 half8 __attribute__((ext_vector_type(8)));
typedef float f32x4 __attribute__((ext_vector_type(4)));

__device__ __forceinline__ void pk_atomic_add(_Float16* p, float a, float b) {
  __half2 v = __floats2half2_rn(a, b);
  unsafeAtomicAdd(reinterpret_cast<__half2*>(p), v);
}

// agg1[n,o] = f16(c1_bias[o] + sum_i x[n,i]*c1_root[i,o])
__global__ __launch_bounds__(256) void k_init1(const float* __restrict__ x,
    const float* __restrict__ root, const float* __restrict__ bias,
    _Float16* __restrict__ agg1) {
  int t = blockIdx.x * 256 + threadIdx.x;
  int n = t >> 5, o = t & 31;
  if (n >= NNODES) return;
  float acc = bias[o];
  #pragma unroll
  for (int i = 0; i < FN; i++) acc += x[n * FN + i] * root[i * H1C + o];
  agg1[n * H1C + o] = (_Float16)acc;
}

// Pre-swizzled f16 W-fragments for conv1 MFMA (UNCHANGED index math, r5-verified;
// with swapped mfma args this array serves as the A-operand: A[row=o][k]).
__global__ __launch_bounds__(256) void k_prepB1(const float* __restrict__ w2,
    const float* __restrict__ b2, _Float16* __restrict__ B1h) {
  int t = blockIdx.x * 256 + threadIdx.x;
  if (t >= 2 * 12 * 64 * 8) return;
  int j = t & 7;
  int lane = (t >> 3) & 63;
  int rest = t >> 9;
  int step = rest % 12;
  int ot = rest / 12;
  int q = (lane >> 4) * 8 + j;
  int o = (lane & 15) + ot * 16;
  float v;
  if (step < 11) v = w2[q * (FN * H1C) + step * H1C + o];
  else v = (q < FN) ? b2[q * H1C + o] : 0.f;
  B1h[t] = (_Float16)v;
}

// conv1 edge pass via MFMA — r10 structure with SWAPPED mfma operands:
// C[row=channel][col=edge]; each lane owns 4 consecutive channels of its own
// edge -> 4 pk_add_f16 atomics per g-iter (halved atomic count).
__global__ __launch_bounds__(256, 3) void k_edge1_mfma(
    const float* __restrict__ x, const int* __restrict__ ei,
    const float* __restrict__ ea, const float* __restrict__ w1,
    const float* __restrict__ b1, const _Float16* __restrict__ B1h,
    _Float16* __restrict__ agg1) {
  __shared__ _Float16 Bl[12288];        // 24 KB W-frags
  __shared__ _Float16 h_sl[4][256][8];  // 16 KB h slices
  __shared__ _Float16 xs_sl[2][256][8]; // 8 KB xs slices (slices 2,3 all-zero)
  __shared__ int s_dst[256];
  int tid = threadIdx.x;
  {
    const int4* s = (const int4*)B1h;   // 1536 int4
    int4* d = (int4*)Bl;
    #pragma unroll
    for (int q = 0; q < 6; q++) d[q * 256 + tid] = s[q * 256 + tid];
  }
  int e = blockIdx.x * 256 + tid;   // NEDGES % 256 == 0
  int src = ei[e];
  s_dst[tid] = ei[NEDGES + e];
  float4 a4 = *reinterpret_cast<const float4*>(ea + e * 4);
  float h[32];
  #pragma unroll
  for (int k = 0; k < 32; k++) {
    float v = b1[k] + a4.x * w1[k] + a4.y * w1[32 + k] + a4.z * w1[64 + k] + a4.w * w1[96 + k];
    h[k] = v > 0.f ? v : 0.f;
  }
  #pragma unroll
  for (int s = 0; s < 4; s++) {
    half8 t8;
    #pragma unroll
    for (int j = 0; j < 8; j++) t8[j] = (_Float16)h[s * 8 + j];
    *reinterpret_cast<half8*>(&h_sl[s][tid][0]) = t8;
  }
  float xsv[FN];
  #pragma unroll
  for (int i = 0; i < FN; i++) xsv[i] = x[src * FN + i];
  #pragma unroll
  for (int s = 0; s < 2; s++) {
    half8 t8;
    #pragma unroll
    for (int j = 0; j < 8; j++) {
      int k = s * 8 + j;
      t8[j] = (k < FN) ? (_Float16)xsv[k] : (_Float16)0.f;
    }
    *reinterpret_cast<half8*>(&xs_sl[s][tid][0]) = t8;
  }
  __syncthreads();
  int lane = tid & 63;
  int w = tid >> 6;
  int halfk = lane >> 4;
  int er = lane & 15;
  #pragma unroll 1
  for (int g = 0; g < 4; g++) {
    int eb = w * 64 + g * 16;
    int el = eb + er;
    half8 hs8 = *reinterpret_cast<const half8*>(&h_sl[halfk][el][0]);
    half8 xs8;
    if (halfk < 2) xs8 = *reinterpret_cast<const half8*>(&xs_sl[halfk][el][0]);
    else xs8 = half8{};   // K rows 16..31 of the bias step are zero
    f32x4 acc0 = {0.f, 0.f, 0.f, 0.f};
    f32x4 acc1 = {0.f, 0.f, 0.f, 0.f};
    {
      half8 b0 = *reinterpret_cast<const half8*>(&Bl[11 * 512 + lane * 8]);
      half8 b1f = *reinterpret_cast<const half8*>(&Bl[6144 + 11 * 512 + lane * 8]);
      acc0 = __builtin_amdgcn_mfma_f32_16x16x32_f16(b0, xs8, acc0, 0, 0, 0);   // swapped
      acc1 = __builtin_amdgcn_mfma_f32_16x16x32_f16(b1f, xs8, acc1, 0, 0, 0);  // swapped
    }
    #pragma unroll
    for (int i = 0; i < FN; i++) {
      _Float16 xh = xs_sl[i >> 3][el][i & 7];
      half8 xsp;
      #pragma unroll
      for (int j = 0; j < 8; j++) xsp[j] = xh;
      half8 zf = xsp * hs8;            // v_pk_mul_f16 x4
      half8 b0 = *reinterpret_cast<const half8*>(&Bl[i * 512 + lane * 8]);
      half8 b1f = *reinterpret_cast<const half8*>(&Bl[6144 + i * 512 + lane * 8]);
      acc0 = __builtin_amdgcn_mfma_f32_16x16x32_f16(b0, zf, acc0, 0, 0, 0);    // swapped
      acc1 = __builtin_amdgcn_mfma_f32_16x16x32_f16(b1f, zf, acc1, 0, 0, 0);   // swapped
    }
    // C[row=channel][col=edge]: this lane owns edge er, channels halfk*4..+3
    int d = s_dst[eb + er];
    int c0 = halfk * 4;
    pk_atomic_add(&agg1[d * H1C + c0],          acc0[0], acc0[1]);
    pk_atomic_add(&agg1[d * H1C + c0 + 2],      acc0[2], acc0[3]);
    pk_atomic_add(&agg1[d * H1C + 16 + c0],     acc1[0], acc1[1]);
    pk_atomic_add(&agg1[d * H1C + 16 + c0 + 2], acc1[2], acc1[3]);
  }
}

// h1h = relu(agg1) (f16); agg2[n,o] = f16(c2_bias[o] + sum_i relu(agg1)[n,i]*c2_root[i,o])
__global__ __launch_bounds__(256) void k_mid(const _Float16* __restrict__ agg1,
    const float* __restrict__ root2, const float* __restrict__ bias2,
    _Float16* __restrict__ h1h, _Float16* __restrict__ agg2) {
  int t = blockIdx.x * 256 + threadIdx.x;
  int n = t >> 4, o = t & 15;
  if (n >= NNODES) return;
  float hv[32];
  #pragma unroll
  for (int i = 0; i < 32; i++) {
    float v = (float)agg1[n * H1C + i];
    hv[i] = v > 0.f ? v : 0.f;
  }
  h1h[n * H1C + o] = (_Float16)hv[o];
  h1h[n * H1C + o + 16] = (_Float16)hv[o + 16];
  float acc = bias2[o];
  #pragma unroll
  for (int i = 0; i < 32; i++) acc += hv[i] * root2[i * H2C + o];
  agg2[n * H2C + o] = (_Float16)acc;
}

// Pre-swizzled f16 W-fragments for conv2 MFMA (UNCHANGED, r4-verified).
__global__ __launch_bounds__(256) void k_prepB2(const float* __restrict__ w2,
    _Float16* __restrict__ B2h) {
  int t = blockIdx.x * 256 + threadIdx.x;
  if (t >= 32 * 64 * 8) return;
  int kk = t >> 9;
  int l = (t >> 3) & 63;
  int j = t & 7;
  int i = (l >> 4) * 8 + j;
  int o = l & 15;
  B2h[t] = (_Float16)w2[(kk * 32 + i) * H2C + o];
}

// conv2 edge pass via MFMA — swapped operands; 2 pk atomics per g-iter per lane.
__global__ __launch_bounds__(256, 3) void k_edge2_mfma(
    const _Float16* __restrict__ h1h, const int* __restrict__ ei,
    const float* __restrict__ ea, const float* __restrict__ w1,
    const float* __restrict__ b1, const _Float16* __restrict__ B2h,
    _Float16* __restrict__ agg2) {
  __shared__ _Float16 Bl[16384];         // 32 KB
  __shared__ _Float16 h_lds[256][34];    // 17 KB (pad 34 -> conflict-free)
  __shared__ int s_src[256];
  __shared__ int s_dst[256];
  int tid = threadIdx.x;
  {
    const int4* s = (const int4*)B2h;    // 2048 int4
    int4* d = (int4*)Bl;
    #pragma unroll
    for (int q = 0; q < 8; q++) d[q * 256 + tid] = s[q * 256 + tid];
  }
  int e = blockIdx.x * 256 + tid;
  s_src[tid] = ei[e];
  s_dst[tid] = ei[NEDGES + e];
  float4 a4 = *reinterpret_cast<const float4*>(ea + e * 4);
  #pragma unroll
  for (int k = 0; k < 32; k++) {
    float v = b1[k] + a4.x * w1[k] + a4.y * w1[32 + k] + a4.z * w1[64 + k] + a4.w * w1[96 + k];
    h_lds[tid][k] = (_Float16)(v > 0.f ? v : 0.f);
  }
  __syncthreads();
  int lane = tid & 63;
  int w = tid >> 6;
  int halfk = lane >> 4;
  int er = lane & 15;
  #pragma unroll 1
  for (int g = 0; g < 4; g++) {
    int eb = w * 64 + g * 16;
    int el = eb + er;
    int sn = s_src[el];
    half8 hsb = *reinterpret_cast<const half8*>(h1h + sn * H1C + halfk * 8);
    f32x4 acc = {0.f, 0.f, 0.f, 0.f};
    #pragma unroll
    for (int kk = 0; kk < 32; kk++) {
      _Float16 hv = h_lds[el][kk];
      half8 hsp;
      #pragma unroll
      for (int j = 0; j < 8; j++) hsp[j] = hv;
      half8 zf = hsp * hsb;            // v_pk_mul_f16 x4
      half8 bfrag = *reinterpret_cast<const half8*>(&Bl[(kk * 64 + lane) * 8]);
      acc = __builtin_amdgcn_mfma_f32_16x16x32_f16(bfrag, zf, acc, 0, 0, 0);   // swapped
    }
    // C[row=channel][col=edge]: lane owns edge er, channels halfk*4..+3
    int d = s_dst[eb + er];
    int c0 = halfk * 4;
    pk_atomic_add(&agg2[d * H2C + c0],     acc[0], acc[1]);
    pk_atomic_add(&agg2[d * H2C + c0 + 2], acc[2], acc[3]);
  }
}

// pooled[batch[n],o] += relu(agg2[n,o])
__global__ __launch_bounds__(256) void k_pool(const _Float16* __restrict__ agg2,
    const int* __restrict__ batch, float* __restrict__ pooled) {
  int t = blockIdx.x * 256 + threadIdx.x;
  int n = t >> 4, o = t & 15;
  if (n >= NNODES) return;
  float v = (float)agg2[n * H2C + o];
  v = v > 0.f ? v : 0.f;
  atomicAdd(&pooled[batch[n] * H2C + o], v);
}

// out[g] = relu(pooled[g]@fc1_w + fc1_b) @ out_w + out_b
__global__ __launch_bounds__(256) void k_head(const float* __restrict__ pooled,
    const float* __restrict__ fc1w, const float* __restrict__ fc1b,
    const float* __restrict__ outw, const float* __restrict__ outb,
    float* __restrict__ out) {
  int g = blockIdx.x * 256 + threadIdx.x;
  if (g >= NGRAPHS) return;
  float p[H2C];
  #pragma unroll
  for (int i = 0; i < H2C; i++) p[i] = pooled[g * H2C + i];
  float acc = outb[0];
  #pragma unroll
  for (int o = 0; o < H1C; o++) {
    float v = fc1b[o];
    #pragma unroll
    for (int i = 0; i < H2C; i++) v += p[i] * fc1w[i * H1C + o];
    v = v > 0.f ? v : 0.f;
    acc += v * outw[o];
  }
  out[g] = acc;
}

extern "C" void kernel_launch(void* const* d_in, const int* in_sizes, int n_in,
                              void* d_out, int out_size, void* d_ws, size_t ws_size,
                              hipStream_t stream) {
  const float* x      = (const float*)d_in[0];
  const int*   ei     = (const int*)d_in[1];
  const float* ea     = (const float*)d_in[2];
  const int*   batch  = (const int*)d_in[3];
  const float* c1w1   = (const float*)d_in[4];
  const float* c1b1   = (const float*)d_in[5];
  const float* c1w2   = (const float*)d_in[6];
  const float* c1b2   = (const float*)d_in[7];
  const float* c1root = (const float*)d_in[8];
  const float* c1bias = (const float*)d_in[9];
  const float* c2w1   = (const float*)d_in[10];
  const float* c2b1   = (const float*)d_in[11];
  const float* c2w2   = (const float*)d_in[12];
  const float* c2b2   = (const float*)d_in[13];
  const float* c2root = (const float*)d_in[14];
  const float* c2bias = (const float*)d_in[15];
  const float* fc1w   = (const float*)d_in[16];
  const float* fc1b   = (const float*)d_in[17];
  const float* outw   = (const float*)d_in[18];
  const float* outb   = (const float*)d_in[19];
  float* out = (float*)d_out;

  _Float16*  agg1   = (_Float16*)d_ws;                     // 6.4 MB
  _Float16*  h1h    = agg1 + NNODES * H1C;                 // 6.4 MB
  _Float16*  agg2   = h1h + NNODES * H1C;                  // 3.2 MB
  float*     pooled = (float*)(agg2 + NNODES * H2C);       // 320 KB
  _Float16*  B2h    = (_Float16*)(pooled + NGRAPHS * H2C); // 32 KB
  _Float16*  B1h    = B2h + 32 * 64 * 8;                   // 24 KB

  hipMemsetAsync(pooled, 0, NGRAPHS * H2C * sizeof(float), stream);

  k_init1<<<(NNODES * H1C + 255) / 256, 256, 0, stream>>>(x, c1root, c1bias, agg1);
  k_prepB1<<<48, 256, 0, stream>>>(c1w2, c1b2, B1h);
  k_prepB2<<<64, 256, 0, stream>>>(c2w2, B2h);
  k_edge1_mfma<<<NEDGES / 256, 256, 0, stream>>>(x, ei, ea, c1w1, c1b1, B1h, agg1);
  k_mid<<<(NNODES * H2C + 255) / 256, 256, 0, stream>>>(agg1, c2root, c2bias, h1h, agg2);
  k_edge2_mfma<<<NEDGES / 256, 256, 0, stream>>>(h1h, ei, ea, c2w1, c2b1, B2h, agg2);
  k_pool<<<(NNODES * H2C + 255) / 256, 256, 0, stream>>>(agg2, batch, pooled);
  k_head<<<(NGRAPHS + 255) / 256, 256, 0, stream>>>(pooled, fc1w, fc1b, outw, outb, out);
}

// Round 12
// 244.012 us; speedup vs baseline: 1.2983x; 1.2983x over previous
//
#include <hip/hip_runtime.h>
#include <hip/hip_fp16.h>

#define NNODES 100000
#define NEDGES 800000
#define NGRAPHS 5000
#define FN 11
#define FE 4
#define H1C 32
#define H2C 16

typedef _Float16 half8 __attribute__((ext_vector_type(8)));
typedef _Float16 half2v __attribute__((ext_vector_type(2)));
typedef float f32x4 __attribute__((ext_vector_type(4)));

__device__ __forceinline__ void pk_atomic_add(_Float16* p, float a, float b) {
  __half2 v = __floats2half2_rn(a, b);
  unsafeAtomicAdd(reinterpret_cast<__half2*>(p), v);
}

// ---------------- counting-sort prepass ----------------
__global__ __launch_bounds__(256) void k_count(const int* __restrict__ ei,
    int* __restrict__ cnt) {
  int e = blockIdx.x * 256 + threadIdx.x;
  atomicAdd(&cnt[ei[NEDGES + e]], 1);
}

__global__ __launch_bounds__(1024) void k_scan_blk(const int* __restrict__ cnt,
    int* __restrict__ offs, int* __restrict__ bsum) {
  __shared__ int s[1024];
  int tid = threadIdx.x;
  int n = blockIdx.x * 1024 + tid;
  int v = (n < NNODES) ? cnt[n] : 0;
  s[tid] = v;
  __syncthreads();
  #pragma unroll
  for (int ofs = 1; ofs < 1024; ofs <<= 1) {
    int t = (tid >= ofs) ? s[tid - ofs] : 0;
    __syncthreads();
    s[tid] += t;
    __syncthreads();
  }
  if (n < NNODES) offs[n] = s[tid] - v;   // exclusive
  if (tid == 1023) bsum[blockIdx.x] = s[1023];
}

__global__ __launch_bounds__(128) void k_scan_top(int* __restrict__ bsum) {
  __shared__ int s[128];
  int tid = threadIdx.x;
  int v = (tid < 98) ? bsum[tid] : 0;
  s[tid] = v;
  __syncthreads();
  #pragma unroll
  for (int ofs = 1; ofs < 128; ofs <<= 1) {
    int t = (tid >= ofs) ? s[tid - ofs] : 0;
    __syncthreads();
    s[tid] += t;
    __syncthreads();
  }
  if (tid < 98) bsum[tid] = s[tid] - v;   // exclusive
}

// cursor (stored back into cnt) = global run start
__global__ __launch_bounds__(1024) void k_scan_add(const int* __restrict__ offs,
    const int* __restrict__ bsum, int* __restrict__ cnt) {
  int n = blockIdx.x * 1024 + threadIdx.x;
  if (n < NNODES) cnt[n] = offs[n] + bsum[blockIdx.x];
}

__global__ __launch_bounds__(256) void k_permute(const int* __restrict__ ei,
    const float* __restrict__ ea, int* __restrict__ cursor,
    int* __restrict__ src_p, int* __restrict__ dst_p, float4* __restrict__ ea_p) {
  int e = blockIdx.x * 256 + threadIdx.x;
  int d = ei[NEDGES + e];
  int pos = atomicAdd(&cursor[d], 1);
  src_p[pos] = ei[e];
  dst_p[pos] = d;
  ea_p[pos] = *reinterpret_cast<const float4*>(ea + (size_t)e * 4);
}

// ---------------- model kernels ----------------
// agg1[n,o] = f16(c1_bias[o] + sum_i x[n,i]*c1_root[i,o])
__global__ __launch_bounds__(256) void k_init1(const float* __restrict__ x,
    const float* __restrict__ root, const float* __restrict__ bias,
    _Float16* __restrict__ agg1) {
  int t = blockIdx.x * 256 + threadIdx.x;
  int n = t >> 5, o = t & 31;
  if (n >= NNODES) return;
  float acc = bias[o];
  #pragma unroll
  for (int i = 0; i < FN; i++) acc += x[n * FN + i] * root[i * H1C + o];
  agg1[n * H1C + o] = (_Float16)acc;
}

// Pre-swizzled f16 B-fragments for conv1 MFMA (index math verified r5).
__global__ __launch_bounds__(256) void k_prepB1(const float* __restrict__ w2,
    const float* __restrict__ b2, _Float16* __restrict__ B1h) {
  int t = blockIdx.x * 256 + threadIdx.x;
  if (t >= 2 * 12 * 64 * 8) return;
  int j = t & 7;
  int lane = (t >> 3) & 63;
  int rest = t >> 9;
  int step = rest % 12;
  int ot = rest / 12;
  int q = (lane >> 4) * 8 + j;
  int o = (lane & 15) + ot * 16;
  float v;
  if (step < 11) v = w2[q * (FN * H1C) + step * H1C + o];
  else v = (q < FN) ? b2[q * H1C + o] : 0.f;
  B1h[t] = (_Float16)v;
}

// conv1 edge pass: r10-verified MFMA path on dst-sorted edges; epilogue =
// LDS C-store + segmented-run reduction + coalesced pk_add_f16 atomics.
__global__ __launch_bounds__(256, 2) void k_edge1_mfma(
    const float* __restrict__ x, const int* __restrict__ src_p,
    const int* __restrict__ dst_p, const float4* __restrict__ ea_p,
    const float* __restrict__ w1, const float* __restrict__ b1,
    const _Float16* __restrict__ B1h, _Float16* __restrict__ agg1) {
  __shared__ _Float16 Bl[12288];        // 24 KB B-frags
  __shared__ _Float16 h_sl[4][256][8];  // 16 KB h slices
  __shared__ _Float16 xs_sl[2][256][8]; // 8 KB xs slices
  __shared__ _Float16 s_acc[256][34];   // 17 KB C-frags (pad 34 -> 4B-aligned pairs)
  __shared__ int s_dst[256];
  int tid = threadIdx.x;
  {
    const int4* s = (const int4*)B1h;
    int4* d = (int4*)Bl;
    #pragma unroll
    for (int q = 0; q < 6; q++) d[q * 256 + tid] = s[q * 256 + tid];
  }
  int e = blockIdx.x * 256 + tid;   // NEDGES % 256 == 0
  int src = src_p[e];
  s_dst[tid] = dst_p[e];
  float4 a4 = ea_p[e];
  float h[32];
  #pragma unroll
  for (int k = 0; k < 32; k++) {
    float v = b1[k] + a4.x * w1[k] + a4.y * w1[32 + k] + a4.z * w1[64 + k] + a4.w * w1[96 + k];
    h[k] = v > 0.f ? v : 0.f;
  }
  #pragma unroll
  for (int s = 0; s < 4; s++) {
    half8 t8;
    #pragma unroll
    for (int j = 0; j < 8; j++) t8[j] = (_Float16)h[s * 8 + j];
    *reinterpret_cast<half8*>(&h_sl[s][tid][0]) = t8;
  }
  float xsv[FN];
  #pragma unroll
  for (int i = 0; i < FN; i++) xsv[i] = x[src * FN + i];
  #pragma unroll
  for (int s = 0; s < 2; s++) {
    half8 t8;
    #pragma unroll
    for (int j = 0; j < 8; j++) {
      int k = s * 8 + j;
      t8[j] = (k < FN) ? (_Float16)xsv[k] : (_Float16)0.f;
    }
    *reinterpret_cast<half8*>(&xs_sl[s][tid][0]) = t8;
  }
  __syncthreads();
  int lane = tid & 63;
  int w = tid >> 6;
  int halfk = lane >> 4;
  int er = lane & 15;
  #pragma unroll 1
  for (int g = 0; g < 4; g++) {
    int eb = w * 64 + g * 16;
    int el = eb + er;
    half8 hs8 = *reinterpret_cast<const half8*>(&h_sl[halfk][el][0]);
    half8 xs8;
    if (halfk < 2) xs8 = *reinterpret_cast<const half8*>(&xs_sl[halfk][el][0]);
    else xs8 = half8{};
    f32x4 acc0 = {0.f, 0.f, 0.f, 0.f};
    f32x4 acc1 = {0.f, 0.f, 0.f, 0.f};
    {
      half8 b0 = *reinterpret_cast<const half8*>(&Bl[11 * 512 + lane * 8]);
      half8 b1f = *reinterpret_cast<const half8*>(&Bl[6144 + 11 * 512 + lane * 8]);
      acc0 = __builtin_amdgcn_mfma_f32_16x16x32_f16(xs8, b0, acc0, 0, 0, 0);
      acc1 = __builtin_amdgcn_mfma_f32_16x16x32_f16(xs8, b1f, acc1, 0, 0, 0);
    }
    #pragma unroll
    for (int i = 0; i < FN; i++) {
      _Float16 xh = xs_sl[i >> 3][el][i & 7];
      half8 xsp;
      #pragma unroll
      for (int j = 0; j < 8; j++) xsp[j] = xh;
      half8 af = xsp * hs8;
      half8 b0 = *reinterpret_cast<const half8*>(&Bl[i * 512 + lane * 8]);
      half8 b1f = *reinterpret_cast<const half8*>(&Bl[6144 + i * 512 + lane * 8]);
      acc0 = __builtin_amdgcn_mfma_f32_16x16x32_f16(af, b0, acc0, 0, 0, 0);
      acc1 = __builtin_amdgcn_mfma_f32_16x16x32_f16(af, b1f, acc1, 0, 0, 0);
    }
    // C[row=edge-in-group][col=channel er]: store to LDS instead of atomics
    #pragma unroll
    for (int r = 0; r < 4; r++) {
      int erow = eb + halfk * 4 + r;
      s_acc[erow][er] = (_Float16)acc0[r];
      s_acc[erow][er + 16] = (_Float16)acc1[r];
    }
  }
  __syncthreads();
  // segmented reduction over sorted dst: thread = (channel pair, 16-edge segment)
  int p2 = (tid & 15) * 2;
  int jseg = tid >> 4;
  int ebeg = jseg * 16;
  int run_d = s_dst[ebeg];
  float s0 = 0.f, s1 = 0.f;
  #pragma unroll 1
  for (int e2 = ebeg; e2 < ebeg + 16; e2++) {
    int d2 = s_dst[e2];
    if (d2 != run_d) {
      pk_atomic_add(&agg1[run_d * H1C + p2], s0, s1);
      run_d = d2; s0 = 0.f; s1 = 0.f;
    }
    half2v v = *reinterpret_cast<const half2v*>(&s_acc[e2][p2]);
    s0 += (float)v[0]; s1 += (float)v[1];
  }
  pk_atomic_add(&agg1[run_d * H1C + p2], s0, s1);
}

// h1h = relu(agg1); agg2[n,o] = f16(c2_bias[o] + sum_i relu(agg1)[n,i]*c2_root[i,o])
__global__ __launch_bounds__(256) void k_mid(const _Float16* __restrict__ agg1,
    const float* __restrict__ root2, const float* __restrict__ bias2,
    _Float16* __restrict__ h1h, _Float16* __restrict__ agg2) {
  int t = blockIdx.x * 256 + threadIdx.x;
  int n = t >> 4, o = t & 15;
  if (n >= NNODES) return;
  float hv[32];
  #pragma unroll
  for (int i = 0; i < 32; i++) {
    float v = (float)agg1[n * H1C + i];
    hv[i] = v > 0.f ? v : 0.f;
  }
  h1h[n * H1C + o] = (_Float16)hv[o];
  h1h[n * H1C + o + 16] = (_Float16)hv[o + 16];
  float acc = bias2[o];
  #pragma unroll
  for (int i = 0; i < 32; i++) acc += hv[i] * root2[i * H2C + o];
  agg2[n * H2C + o] = (_Float16)acc;
}

// Pre-swizzled f16 B-fragments for conv2 MFMA (index math verified r4).
__global__ __launch_bounds__(256) void k_prepB2(const float* __restrict__ w2,
    _Float16* __restrict__ B2h) {
  int t = blockIdx.x * 256 + threadIdx.x;
  if (t >= 32 * 64 * 8) return;
  int kk = t >> 9;
  int l = (t >> 3) & 63;
  int j = t & 7;
  int i = (l >> 4) * 8 + j;
  int o = l & 15;
  B2h[t] = (_Float16)w2[(kk * 32 + i) * H2C + o];
}

// conv2 edge pass: r10 MFMA path on sorted edges + segmented-run epilogue.
__global__ __launch_bounds__(256, 2) void k_edge2_mfma(
    const _Float16* __restrict__ h1h, const int* __restrict__ src_p,
    const int* __restrict__ dst_p, const float4* __restrict__ ea_p,
    const float* __restrict__ w1, const float* __restrict__ b1,
    const _Float16* __restrict__ B2h, _Float16* __restrict__ agg2) {
  __shared__ _Float16 Bl[16384];         // 32 KB
  __shared__ _Float16 h_lds[256][34];    // 17 KB
  __shared__ _Float16 s_acc[256][18];    // 9 KB C-frags (pad 18 -> aligned pairs)
  __shared__ int s_src[256];
  __shared__ int s_dst[256];
  int tid = threadIdx.x;
  {
    const int4* s = (const int4*)B2h;
    int4* d = (int4*)Bl;
    #pragma unroll
    for (int q = 0; q < 8; q++) d[q * 256 + tid] = s[q * 256 + tid];
  }
  int e = blockIdx.x * 256 + tid;
  s_src[tid] = src_p[e];
  s_dst[tid] = dst_p[e];
  float4 a4 = ea_p[e];
  #pragma unroll
  for (int k = 0; k < 32; k++) {
    float v = b1[k] + a4.x * w1[k] + a4.y * w1[32 + k] + a4.z * w1[64 + k] + a4.w * w1[96 + k];
    h_lds[tid][k] = (_Float16)(v > 0.f ? v : 0.f);
  }
  __syncthreads();
  int lane = tid & 63;
  int w = tid >> 6;
  int halfk = lane >> 4;
  int er = lane & 15;
  #pragma unroll 1
  for (int g = 0; g < 4; g++) {
    int eb = w * 64 + g * 16;
    int el = eb + er;
    int sn = s_src[el];
    half8 hsb = *reinterpret_cast<const half8*>(h1h + sn * H1C + halfk * 8);
    f32x4 acc = {0.f, 0.f, 0.f, 0.f};
    #pragma unroll
    for (int kk = 0; kk < 32; kk++) {
      _Float16 hv = h_lds[el][kk];
      half8 hsp;
      #pragma unroll
      for (int j = 0; j < 8; j++) hsp[j] = hv;
      half8 af = hsp * hsb;
      half8 bfrag = *reinterpret_cast<const half8*>(&Bl[(kk * 64 + lane) * 8]);
      acc = __builtin_amdgcn_mfma_f32_16x16x32_f16(af, bfrag, acc, 0, 0, 0);
    }
    #pragma unroll
    for (int r = 0; r < 4; r++) {
      s_acc[eb + halfk * 4 + r][er] = (_Float16)acc[r];
    }
  }
  __syncthreads();
  // segmented reduction: thread = (channel pair p2, 8-edge segment)
  int p2 = (tid & 7) * 2;
  int jseg = tid >> 3;
  int ebeg = jseg * 8;
  int run_d = s_dst[ebeg];
  float s0 = 0.f, s1 = 0.f;
  #pragma unroll 1
  for (int e2 = ebeg; e2 < ebeg + 8; e2++) {
    int d2 = s_dst[e2];
    if (d2 != run_d) {
      pk_atomic_add(&agg2[run_d * H2C + p2], s0, s1);
      run_d = d2; s0 = 0.f; s1 = 0.f;
    }
    half2v v = *reinterpret_cast<const half2v*>(&s_acc[e2][p2]);
    s0 += (float)v[0]; s1 += (float)v[1];
  }
  pk_atomic_add(&agg2[run_d * H2C + p2], s0, s1);
}

// pooled[batch[n],o] += relu(agg2[n,o])
__global__ __launch_bounds__(256) void k_pool(const _Float16* __restrict__ agg2,
    const int* __restrict__ batch, float* __restrict__ pooled) {
  int t = blockIdx.x * 256 + threadIdx.x;
  int n = t >> 4, o = t & 15;
  if (n >= NNODES) return;
  float v = (float)agg2[n * H2C + o];
  v = v > 0.f ? v : 0.f;
  atomicAdd(&pooled[batch[n] * H2C + o], v);
}

// out[g] = relu(pooled[g]@fc1_w + fc1_b) @ out_w + out_b
__global__ __launch_bounds__(256) void k_head(const float* __restrict__ pooled,
    const float* __restrict__ fc1w, const float* __restrict__ fc1b,
    const float* __restrict__ outw, const float* __restrict__ outb,
    float* __restrict__ out) {
  int g = blockIdx.x * 256 + threadIdx.x;
  if (g >= NGRAPHS) return;
  float p[H2C];
  #pragma unroll
  for (int i = 0; i < H2C; i++) p[i] = pooled[g * H2C + i];
  float acc = outb[0];
  #pragma unroll
  for (int o = 0; o < H1C; o++) {
    float v = fc1b[o];
    #pragma unroll
    for (int i = 0; i < H2C; i++) v += p[i] * fc1w[i * H1C + o];
    v = v > 0.f ? v : 0.f;
    acc += v * outw[o];
  }
  out[g] = acc;
}

extern "C" void kernel_launch(void* const* d_in, const int* in_sizes, int n_in,
                              void* d_out, int out_size, void* d_ws, size_t ws_size,
                              hipStream_t stream) {
  const float* x      = (const float*)d_in[0];
  const int*   ei     = (const int*)d_in[1];
  const float* ea     = (const float*)d_in[2];
  const int*   batch  = (const int*)d_in[3];
  const float* c1w1   = (const float*)d_in[4];
  const float* c1b1   = (const float*)d_in[5];
  const float* c1w2   = (const float*)d_in[6];
  const float* c1b2   = (const float*)d_in[7];
  const float* c1root = (const float*)d_in[8];
  const float* c1bias = (const float*)d_in[9];
  const float* c2w1   = (const float*)d_in[10];
  const float* c2b1   = (const float*)d_in[11];
  const float* c2w2   = (const float*)d_in[12];
  const float* c2b2   = (const float*)d_in[13];
  const float* c2root = (const float*)d_in[14];
  const float* c2bias = (const float*)d_in[15];
  const float* fc1w   = (const float*)d_in[16];
  const float* fc1b   = (const float*)d_in[17];
  const float* outw   = (const float*)d_in[18];
  const float* outb   = (const float*)d_in[19];
  float* out = (float*)d_out;

  float4*    ea_p   = (float4*)d_ws;                       // 12.8 MB (16B aligned)
  float*     pooled = (float*)(ea_p + NEDGES);             // 320 KB
  int*       cnt    = (int*)(pooled + NGRAPHS * H2C);      // 400 KB (reused as cursor)
  int*       offs   = cnt + NNODES;                        // 400 KB
  int*       bsum   = offs + NNODES;                       // 512 B
  int*       src_p  = bsum + 128;                          // 3.2 MB
  int*       dst_p  = src_p + NEDGES;                      // 3.2 MB
  _Float16*  agg1   = (_Float16*)(dst_p + NEDGES);         // 6.4 MB
  _Float16*  h1h    = agg1 + NNODES * H1C;                 // 6.4 MB
  _Float16*  agg2   = h1h + NNODES * H1C;                  // 3.2 MB
  _Float16*  B1h    = agg2 + NNODES * H2C;                 // 24 KB
  _Float16*  B2h    = B1h + 2 * 12 * 64 * 8;               // 32 KB

  hipMemsetAsync(pooled, 0, NGRAPHS * H2C * sizeof(float), stream);
  hipMemsetAsync(cnt, 0, NNODES * sizeof(int), stream);

  // counting sort by dst
  k_count<<<NEDGES / 256, 256, 0, stream>>>(ei, cnt);
  k_scan_blk<<<98, 1024, 0, stream>>>(cnt, offs, bsum);
  k_scan_top<<<1, 128, 0, stream>>>(bsum);
  k_scan_add<<<98, 1024, 0, stream>>>(offs, bsum, cnt);   // cnt := cursor
  k_permute<<<NEDGES / 256, 256, 0, stream>>>(ei, ea, cnt, src_p, dst_p, ea_p);

  k_init1<<<(NNODES * H1C + 255) / 256, 256, 0, stream>>>(x, c1root, c1bias, agg1);
  k_prepB1<<<48, 256, 0, stream>>>(c1w2, c1b2, B1h);
  k_prepB2<<<64, 256, 0, stream>>>(c2w2, B2h);
  k_edge1_mfma<<<NEDGES / 256, 256, 0, stream>>>(x, src_p, dst_p, ea_p, c1w1, c1b1, B1h, agg1);
  k_mid<<<(NNODES * H2C + 255) / 256, 256, 0, stream>>>(agg1, c2root, c2bias, h1h, agg2);
  k_edge2_mfma<<<NEDGES / 256, 256, 0, stream>>>(h1h, src_p, dst_p, ea_p, c2w1, c2b1, B2h, agg2);
  k_pool<<<(NNODES * H2C + 255) / 256, 256, 0, stream>>>(agg2, batch, pooled);
  k_head<<<(NGRAPHS + 255) / 256, 256, 0, stream>>>(pooled, fc1w, fc1b, outw, outb, out);
}

// Round 13
// 158.645 us; speedup vs baseline: 1.9968x; 1.5381x over previous
//
#include <hip/hip_runtime.h>
#include <hip/hip_fp16.h>

#define NNODES 100000
#define NEDGES 800000
#define NGRAPHS 5000
#define FN 11
#define FE 4
#define H1C 32
#define H2C 16

typedef _Float16 half8 __attribute__((ext_vector_type(8)));
typedef float f32x4 __attribute__((ext_vector_type(4)));

__device__ __forceinline__ void pk_atomic_add(_Float16* p, float a, float b) {
  __half2 v = __floats2half2_rn(a, b);
  unsafeAtomicAdd(reinterpret_cast<__half2*>(p), v);
}

// agg1[n,o] = f16(c1_bias[o] + sum_i x[n,i]*c1_root[i,o])
__global__ __launch_bounds__(256) void k_init1(const float* __restrict__ x,
    const float* __restrict__ root, const float* __restrict__ bias,
    _Float16* __restrict__ agg1) {
  int t = blockIdx.x * 256 + threadIdx.x;
  int n = t >> 5, o = t & 31;
  if (n >= NNODES) return;
  float acc = bias[o];
  #pragma unroll
  for (int i = 0; i < FN; i++) acc += x[n * FN + i] * root[i * H1C + o];
  agg1[n * H1C + o] = (_Float16)acc;
}

// Pre-swizzled f16 B-fragments for conv1 MFMA (index math verified r5).
__global__ __launch_bounds__(256) void k_prepB1(const float* __restrict__ w2,
    const float* __restrict__ b2, _Float16* __restrict__ B1h) {
  int t = blockIdx.x * 256 + threadIdx.x;
  if (t >= 2 * 12 * 64 * 8) return;
  int j = t & 7;
  int lane = (t >> 3) & 63;
  int rest = t >> 9;
  int step = rest % 12;
  int ot = rest / 12;
  int q = (lane >> 4) * 8 + j;
  int o = (lane & 15) + ot * 16;
  float v;
  if (step < 11) v = w2[q * (FN * H1C) + step * H1C + o];
  else v = (q < FN) ? b2[q * H1C + o] : 0.f;
  B1h[t] = (_Float16)v;
}

// conv1 edge pass via MFMA — exact r10 structure; epilogue pairs adjacent
// channels via shfl_xor and fires packed __half2 atomics (half the lane-ops,
// same full-line coalescing: even lanes cover ch 0-15, odd lanes ch 16-31).
__global__ __launch_bounds__(256, 3) void k_edge1_mfma(
    const float* __restrict__ x, const int* __restrict__ ei,
    const float* __restrict__ ea, const float* __restrict__ w1,
    const float* __restrict__ b1, const _Float16* __restrict__ B1h,
    _Float16* __restrict__ agg1) {
  __shared__ _Float16 Bl[12288];        // 24 KB B-frags
  __shared__ _Float16 h_sl[4][256][8];  // 16 KB h slices
  __shared__ _Float16 xs_sl[2][256][8]; // 8 KB xs slices (slices 2,3 all-zero)
  __shared__ int s_dst[256];
  int tid = threadIdx.x;
  {
    const int4* s = (const int4*)B1h;   // 1536 int4
    int4* d = (int4*)Bl;
    #pragma unroll
    for (int q = 0; q < 6; q++) d[q * 256 + tid] = s[q * 256 + tid];
  }
  int e = blockIdx.x * 256 + tid;   // NEDGES % 256 == 0
  int src = ei[e];
  s_dst[tid] = ei[NEDGES + e];
  float4 a4 = *reinterpret_cast<const float4*>(ea + e * 4);
  float h[32];
  #pragma unroll
  for (int k = 0; k < 32; k++) {
    float v = b1[k] + a4.x * w1[k] + a4.y * w1[32 + k] + a4.z * w1[64 + k] + a4.w * w1[96 + k];
    h[k] = v > 0.f ? v : 0.f;
  }
  #pragma unroll
  for (int s = 0; s < 4; s++) {
    half8 t8;
    #pragma unroll
    for (int j = 0; j < 8; j++) t8[j] = (_Float16)h[s * 8 + j];
    *reinterpret_cast<half8*>(&h_sl[s][tid][0]) = t8;
  }
  float xsv[FN];
  #pragma unroll
  for (int i = 0; i < FN; i++) xsv[i] = x[src * FN + i];
  #pragma unroll
  for (int s = 0; s < 2; s++) {
    half8 t8;
    #pragma unroll
    for (int j = 0; j < 8; j++) {
      int k = s * 8 + j;
      t8[j] = (k < FN) ? (_Float16)xsv[k] : (_Float16)0.f;
    }
    *reinterpret_cast<half8*>(&xs_sl[s][tid][0]) = t8;
  }
  __syncthreads();
  int lane = tid & 63;
  int w = tid >> 6;
  int halfk = lane >> 4;
  int er = lane & 15;
  #pragma unroll 1
  for (int g = 0; g < 4; g++) {
    int eb = w * 64 + g * 16;
    int el = eb + er;
    half8 hs8 = *reinterpret_cast<const half8*>(&h_sl[halfk][el][0]);
    half8 xs8;
    if (halfk < 2) xs8 = *reinterpret_cast<const half8*>(&xs_sl[halfk][el][0]);
    else xs8 = half8{};   // K rows 16..31 of the bias step are zero
    f32x4 acc0 = {0.f, 0.f, 0.f, 0.f};
    f32x4 acc1 = {0.f, 0.f, 0.f, 0.f};
    {
      half8 b0 = *reinterpret_cast<const half8*>(&Bl[11 * 512 + lane * 8]);
      half8 b1f = *reinterpret_cast<const half8*>(&Bl[6144 + 11 * 512 + lane * 8]);
      acc0 = __builtin_amdgcn_mfma_f32_16x16x32_f16(xs8, b0, acc0, 0, 0, 0);
      acc1 = __builtin_amdgcn_mfma_f32_16x16x32_f16(xs8, b1f, acc1, 0, 0, 0);
    }
    #pragma unroll
    for (int i = 0; i < FN; i++) {
      _Float16 xh = xs_sl[i >> 3][el][i & 7];
      half8 xsp;
      #pragma unroll
      for (int j = 0; j < 8; j++) xsp[j] = xh;
      half8 af = xsp * hs8;            // v_pk_mul_f16 x4
      half8 b0 = *reinterpret_cast<const half8*>(&Bl[i * 512 + lane * 8]);
      half8 b1f = *reinterpret_cast<const half8*>(&Bl[6144 + i * 512 + lane * 8]);
      acc0 = __builtin_amdgcn_mfma_f32_16x16x32_f16(af, b0, acc0, 0, 0, 0);
      acc1 = __builtin_amdgcn_mfma_f32_16x16x32_f16(af, b1f, acc1, 0, 0, 0);
    }
    // paired-channel packed atomics: even lanes do (er,er+1) of acc0,
    // odd lanes do (16+er-1,16+er) of acc1 — one instr per r, all lanes on.
    #pragma unroll
    for (int r = 0; r < 4; r++) {
      int d = s_dst[eb + halfk * 4 + r];
      float p0 = __shfl_xor(acc0[r], 1, 64);
      float p1 = __shfl_xor(acc1[r], 1, 64);
      int odd = er & 1;
      int ch = odd ? (16 + er - 1) : er;
      float lo = odd ? p1 : acc0[r];
      float hi = odd ? acc1[r] : p0;
      pk_atomic_add(&agg1[d * H1C + ch], lo, hi);
    }
  }
}

// h1h = relu(agg1) (f16); agg2 base = f16(c2_bias + relu(agg1)@c2_root)
__global__ __launch_bounds__(256) void k_mid(const _Float16* __restrict__ agg1,
    const float* __restrict__ root2, const float* __restrict__ bias2,
    _Float16* __restrict__ h1h, _Float16* __restrict__ agg2) {
  int t = blockIdx.x * 256 + threadIdx.x;
  int n = t >> 4, o = t & 15;
  if (n >= NNODES) return;
  float hv[32];
  #pragma unroll
  for (int i = 0; i < 32; i++) {
    float v = (float)agg1[n * H1C + i];
    hv[i] = v > 0.f ? v : 0.f;
  }
  h1h[n * H1C + o] = (_Float16)hv[o];
  h1h[n * H1C + o + 16] = (_Float16)hv[o + 16];
  float acc = bias2[o];
  #pragma unroll
  for (int i = 0; i < 32; i++) acc += hv[i] * root2[i * H2C + o];
  agg2[n * H2C + o] = (_Float16)acc;
}

// Pre-swizzled f16 B-fragments for conv2 MFMA (index math verified r4).
__global__ __launch_bounds__(256) void k_prepB2(const float* __restrict__ w2,
    _Float16* __restrict__ B2h) {
  int t = blockIdx.x * 256 + threadIdx.x;
  if (t >= 32 * 64 * 8) return;
  int kk = t >> 9;
  int l = (t >> 3) & 63;
  int j = t & 7;
  int i = (l >> 4) * 8 + j;
  int o = l & 15;
  B2h[t] = (_Float16)w2[(kk * 32 + i) * H2C + o];
}

// conv2 edge pass — r10 structure; epilogue pairs channels via shfl_xor,
// even lanes store row r, odd lanes row r+1 (2 packed atomics per g-iter).
__global__ __launch_bounds__(256, 3) void k_edge2_mfma(
    const _Float16* __restrict__ h1h, const int* __restrict__ ei,
    const float* __restrict__ ea, const float* __restrict__ w1,
    const float* __restrict__ b1, const _Float16* __restrict__ B2h,
    _Float16* __restrict__ agg2) {
  __shared__ _Float16 Bl[16384];         // 32 KB
  __shared__ _Float16 h_lds[256][34];    // 17 KB (pad 34 -> conflict-free)
  __shared__ int s_src[256];
  __shared__ int s_dst[256];
  int tid = threadIdx.x;
  {
    const int4* s = (const int4*)B2h;    // 2048 int4
    int4* d = (int4*)Bl;
    #pragma unroll
    for (int q = 0; q < 8; q++) d[q * 256 + tid] = s[q * 256 + tid];
  }
  int e = blockIdx.x * 256 + tid;
  s_src[tid] = ei[e];
  s_dst[tid] = ei[NEDGES + e];
  float4 a4 = *reinterpret_cast<const float4*>(ea + e * 4);
  #pragma unroll
  for (int k = 0; k < 32; k++) {
    float v = b1[k] + a4.x * w1[k] + a4.y * w1[32 + k] + a4.z * w1[64 + k] + a4.w * w1[96 + k];
    h_lds[tid][k] = (_Float16)(v > 0.f ? v : 0.f);
  }
  __syncthreads();
  int lane = tid & 63;
  int w = tid >> 6;
  int halfk = lane >> 4;
  int er = lane & 15;
  #pragma unroll 1
  for (int g = 0; g < 4; g++) {
    int eb = w * 64 + g * 16;
    int el = eb + er;
    int sn = s_src[el];
    half8 hsb = *reinterpret_cast<const half8*>(h1h + sn * H1C + halfk * 8);
    f32x4 acc = {0.f, 0.f, 0.f, 0.f};
    #pragma unroll
    for (int kk = 0; kk < 32; kk++) {
      _Float16 hv = h_lds[el][kk];
      half8 hsp;
      #pragma unroll
      for (int j = 0; j < 8; j++) hsp[j] = hv;
      half8 af = hsp * hsb;            // v_pk_mul_f16 x4
      half8 bfrag = *reinterpret_cast<const half8*>(&Bl[(kk * 64 + lane) * 8]);
      acc = __builtin_amdgcn_mfma_f32_16x16x32_f16(af, bfrag, acc, 0, 0, 0);
    }
    #pragma unroll
    for (int r2 = 0; r2 < 4; r2 += 2) {
      int d_e = s_dst[eb + halfk * 4 + r2];
      int d_o = s_dst[eb + halfk * 4 + r2 + 1];
      float pe = __shfl_xor(acc[r2], 1, 64);
      float po = __shfl_xor(acc[r2 + 1], 1, 64);
      int odd = er & 1;
      int d = odd ? d_o : d_e;
      int ch = odd ? (er - 1) : er;
      float lo = odd ? po : acc[r2];
      float hi = odd ? acc[r2 + 1] : pe;
      pk_atomic_add(&agg2[d * H2C + ch], lo, hi);
    }
  }
}

// pooled[batch[n],o] += relu(agg2[n,o])
__global__ __launch_bounds__(256) void k_pool(const _Float16* __restrict__ agg2,
    const int* __restrict__ batch, float* __restrict__ pooled) {
  int t = blockIdx.x * 256 + threadIdx.x;
  int n = t >> 4, o = t & 15;
  if (n >= NNODES) return;
  float v = (float)agg2[n * H2C + o];
  v = v > 0.f ? v : 0.f;
  atomicAdd(&pooled[batch[n] * H2C + o], v);
}

// out[g] = relu(pooled[g]@fc1_w + fc1_b) @ out_w + out_b
__global__ __launch_bounds__(256) void k_head(const float* __restrict__ pooled,
    const float* __restrict__ fc1w, const float* __restrict__ fc1b,
    const float* __restrict__ outw, const float* __restrict__ outb,
    float* __restrict__ out) {
  int g = blockIdx.x * 256 + threadIdx.x;
  if (g >= NGRAPHS) return;
  float p[H2C];
  #pragma unroll
  for (int i = 0; i < H2C; i++) p[i] = pooled[g * H2C + i];
  float acc = outb[0];
  #pragma unroll
  for (int o = 0; o < H1C; o++) {
    float v = fc1b[o];
    #pragma unroll
    for (int i = 0; i < H2C; i++) v += p[i] * fc1w[i * H1C + o];
    v = v > 0.f ? v : 0.f;
    acc += v * outw[o];
  }
  out[g] = acc;
}

extern "C" void kernel_launch(void* const* d_in, const int* in_sizes, int n_in,
                              void* d_out, int out_size, void* d_ws, size_t ws_size,
                              hipStream_t stream) {
  const float* x      = (const float*)d_in[0];
  const int*   ei     = (const int*)d_in[1];
  const float* ea     = (const float*)d_in[2];
  const int*   batch  = (const int*)d_in[3];
  const float* c1w1   = (const float*)d_in[4];
  const float* c1b1   = (const float*)d_in[5];
  const float* c1w2   = (const float*)d_in[6];
  const float* c1b2   = (const float*)d_in[7];
  const float* c1root = (const float*)d_in[8];
  const float* c1bias = (const float*)d_in[9];
  const float* c2w1   = (const float*)d_in[10];
  const float* c2b1   = (const float*)d_in[11];
  const float* c2w2   = (const float*)d_in[12];
  const float* c2b2   = (const float*)d_in[13];
  const float* c2root = (const float*)d_in[14];
  const float* c2bias = (const float*)d_in[15];
  const float* fc1w   = (const float*)d_in[16];
  const float* fc1b   = (const float*)d_in[17];
  const float* outw   = (const float*)d_in[18];
  const float* outb   = (const float*)d_in[19];
  float* out = (float*)d_out;

  _Float16*  agg1   = (_Float16*)d_ws;                     // 6.4 MB
  _Float16*  h1h    = agg1 + NNODES * H1C;                 // 6.4 MB
  _Float16*  agg2   = h1h + NNODES * H1C;                  // 3.2 MB
  float*     pooled = (float*)(agg2 + NNODES * H2C);       // 320 KB
  _Float16*  B2h    = (_Float16*)(pooled + NGRAPHS * H2C); // 32 KB
  _Float16*  B1h    = B2h + 32 * 64 * 8;                   // 24 KB

  hipMemsetAsync(pooled, 0, NGRAPHS * H2C * sizeof(float), stream);

  k_init1<<<(NNODES * H1C + 255) / 256, 256, 0, stream>>>(x, c1root, c1bias, agg1);
  k_prepB1<<<48, 256, 0, stream>>>(c1w2, c1b2, B1h);
  k_prepB2<<<64, 256, 0, stream>>>(c2w2, B2h);
  k_edge1_mfma<<<NEDGES / 256, 256, 0, stream>>>(x, ei, ea, c1w1, c1b1, B1h, agg1);
  k_mid<<<(NNODES * H2C + 255) / 256, 256, 0, stream>>>(agg1, c2root, c2bias, h1h, agg2);
  k_edge2_mfma<<<NEDGES / 256, 256, 0, stream>>>(h1h, ei, ea, c2w1, c2b1, B2h, agg2);
  k_pool<<<(NNODES * H2C + 255) / 256, 256, 0, stream>>>(agg2, batch, pooled);
  k_head<<<(NGRAPHS + 255) / 256, 256, 0, stream>>>(pooled, fc1w, fc1b, outw, outb, out);
}